// Round 3
// baseline (10055.029 us; speedup 1.0000x reference)
//
#include <hip/hip_runtime.h>
#include <hip/hip_bf16.h>
#include <stdint.h>

typedef unsigned short ushort_t;
typedef __attribute__((ext_vector_type(4))) float  floatx4;
typedef __attribute__((ext_vector_type(8))) short  shortx8;

static __device__ __forceinline__ float bf2f(ushort_t u) {
    uint32_t x = ((uint32_t)u) << 16;
    return __builtin_bit_cast(float, x);
}
static __device__ __forceinline__ ushort_t f2bf(float f) {
    uint32_t x = __builtin_bit_cast(uint32_t, f);
    uint32_t r = (x + 0x7fffu + ((x >> 16) & 1u)) >> 16;
    return (ushort_t)r;
}
// dtype-branched scalar load (flag uniform -> no divergence)
static __device__ __forceinline__ float loadf(const void* p, size_t i, uint32_t f32) {
    return f32 ? ((const float*)p)[i] : bf2f(((const ushort_t*)p)[i]);
}
// dtype-branched 8-element load (i multiple of 8 -> aligned vector loads)
static __device__ __forceinline__ void load8f(const void* p, size_t i, uint32_t f32, float* o) {
    if (f32) {
        float4 a = *(const float4*)((const float*)p + i);
        float4 b = *(const float4*)((const float*)p + i + 4);
        o[0]=a.x; o[1]=a.y; o[2]=a.z; o[3]=a.w; o[4]=b.x; o[5]=b.y; o[6]=b.z; o[7]=b.w;
    } else {
        shortx8 v = *(const shortx8*)((const ushort_t*)p + i);
#pragma unroll
        for (int e = 0; e < 8; ++e) o[e] = bf2f((ushort_t)v[e]);
    }
}

// ---------------------------------------------------------------------------
// Detect input dtype from x's bit patterns. bf16 N(0,1): exponent in [114,130],
// ~0 outliers. fp32 read as ushorts: ~40% of halves have exp<100 or 0xFF.
// flag = 1 -> inputs/outputs are fp32; flag = 0 -> bf16.
// ---------------------------------------------------------------------------
__global__ __launch_bounds__(256) void detect_dtype(
    const ushort_t* __restrict__ x, uint32_t* __restrict__ flag)
{
    const int tid = threadIdx.x;
    uint32_t bad = 0;
    for (int i = tid; i < 16384; i += 256) {
        uint32_t e = (x[i] >> 7) & 0xFFu;
        if (e >= 0xFFu || (e > 0u && e < 100u)) bad++;
    }
    __shared__ uint32_t s[256];
    s[tid] = bad; __syncthreads();
    for (int st = 128; st > 0; st >>= 1) {
        if (tid < st) s[tid] += s[tid + st];
        __syncthreads();
    }
    if (tid == 0) *flag = (s[0] > 1024u) ? 1u : 0u;
}

// ---------------------------------------------------------------------------
// Prep: tiled transpose  src[slice][K][N] -> dst[slice][N][K]  (dst bf16 in ws)
// ---------------------------------------------------------------------------
__global__ __launch_bounds__(256) void transpose_k(
    const void* __restrict__ src, ushort_t* __restrict__ dst, int K, int N,
    const uint32_t* __restrict__ flag)
{
    const uint32_t f32 = *flag;
    __shared__ ushort_t tile[64][72];
    const size_t so = (size_t)blockIdx.z * (size_t)K * (size_t)N;
    const int k0 = blockIdx.y * 64, n0 = blockIdx.x * 64;
    const int r = threadIdx.x >> 2;
    const int cseg = (threadIdx.x & 3) * 16;
#pragma unroll
    for (int c = 0; c < 16; c += 8) {
        float t8[8];
        load8f(src, so + (size_t)(k0 + r) * N + (n0 + cseg + c), f32, t8);
        shortx8 v;
#pragma unroll
        for (int e = 0; e < 8; ++e) v[e] = (short)f2bf(t8[e]);
        *(shortx8*)&tile[r][cseg + c] = v;
    }
    __syncthreads();
#pragma unroll
    for (int c = 0; c < 16; c += 8) {
        shortx8 v;
#pragma unroll
        for (int i = 0; i < 8; ++i) v[i] = (short)tile[cseg + c + i][r];
        *(shortx8*)&dst[so + (size_t)(n0 + r) * K + (k0 + cseg + c)] = v;
    }
}

// ---------------------------------------------------------------------------
// Prep: bias sums (fp32): bs[dg*512+h] = b_ih + b_hh   (one layer, 4096 elems)
// ---------------------------------------------------------------------------
__global__ __launch_bounds__(256) void bias_kernel(
    const void* __restrict__ bih, const void* __restrict__ bhh,
    float* __restrict__ bs, const uint32_t* __restrict__ flag)
{
    const uint32_t f32 = *flag;
    int i = blockIdx.x * 256 + threadIdx.x;   // 0..4095
    bs[i] = loadf(bih, i, f32) + loadf(bhh, i, f32);
}

// ---------------------------------------------------------------------------
// gx GEMM:  gx[d][t*64+b][g][h] = (X[row,:] * noise[d,g,b,:]) @ W[d,g] + bias
//   X:[16384][K] (dtype: flag if x_use_flag else bf16)   noise:[8][64][K] (flag)
//   WT:[8][512][K] bf16 ws    bsum:[8][512] f32
//   grid: (4, 128, 8)   block 256
// ---------------------------------------------------------------------------
__global__ __launch_bounds__(256, 2) void gx_gemm(
    const void* __restrict__ X, const void* __restrict__ noise,
    const ushort_t* __restrict__ WT, const float* __restrict__ bsum,
    ushort_t* __restrict__ gxout, int K,
    const uint32_t* __restrict__ flag, int x_use_flag)
{
    const uint32_t f32  = *flag;
    const uint32_t xf32 = x_use_flag ? f32 : 0u;
    const int dg  = blockIdx.z;
    const int n0  = blockIdx.x * 128;
    const int m0t = blockIdx.y * 128;
    const int tid = threadIdx.x;
    const int lane = tid & 63;
    const int w    = tid >> 6;
    const int wm = (w & 1) * 64, wn = (w >> 1) * 64;

    __shared__ ushort_t As[128][72];
    __shared__ ushort_t Bs[128][72];

    floatx4 acc[4][4];
#pragma unroll
    for (int i = 0; i < 4; ++i)
#pragma unroll
        for (int j = 0; j < 4; ++j) acc[i][j] = (floatx4){0.f, 0.f, 0.f, 0.f};

    const ushort_t* Wp = WT + (size_t)dg * 512 * K + (size_t)n0 * K;

    for (int k0 = 0; k0 < K; k0 += 64) {
#pragma unroll
        for (int c = 0; c < 4; ++c) {
            int id  = c * 256 + tid;
            int row = id >> 3;
            int kc  = (id & 7) * 8;
            int grow = m0t + row;
            float xv[8], nv[8];
            load8f(X, (size_t)grow * K + k0 + kc, xf32, xv);
            load8f(noise, ((size_t)dg * 64 + (grow & 63)) * K + k0 + kc, f32, nv);
            shortx8 av;
#pragma unroll
            for (int e = 0; e < 8; ++e) av[e] = (short)f2bf(xv[e] * nv[e]);
            *(shortx8*)&As[row][kc] = av;
            *(shortx8*)&Bs[row][kc] = *(const shortx8*)(Wp + (size_t)row * K + k0 + kc);
        }
        __syncthreads();
#pragma unroll
        for (int ks = 0; ks < 2; ++ks) {
            int kb = ks * 32 + (lane >> 4) * 8;
            shortx8 af[4], bfr[4];
#pragma unroll
            for (int i = 0; i < 4; ++i) af[i]  = *(const shortx8*)&As[wm + i * 16 + (lane & 15)][kb];
#pragma unroll
            for (int j = 0; j < 4; ++j) bfr[j] = *(const shortx8*)&Bs[wn + j * 16 + (lane & 15)][kb];
#pragma unroll
            for (int i = 0; i < 4; ++i)
#pragma unroll
                for (int j = 0; j < 4; ++j)
                    acc[i][j] = __builtin_amdgcn_mfma_f32_16x16x32_bf16(af[i], bfr[j], acc[i][j], 0, 0, 0);
        }
        __syncthreads();
    }

    const int d = dg >> 2, g = dg & 3;
#pragma unroll
    for (int i = 0; i < 4; ++i) {
        int rowb = m0t + wm + i * 16 + (lane >> 4) * 4;
#pragma unroll
        for (int j = 0; j < 4; ++j) {
            int col = n0 + wn + j * 16 + (lane & 15);
            float bv = bsum[dg * 512 + col];
#pragma unroll
            for (int r = 0; r < 4; ++r) {
                size_t orow = (size_t)(rowb + r);
                gxout[((size_t)d * 16384 + orow) * 2048 + (size_t)g * 512 + col] =
                    f2bf(acc[i][j][r] + bv);
            }
        }
    }
}

// ---------------------------------------------------------------------------
// Monotonic per-episode device barrier: one counter per (layer,dir,episode).
// ---------------------------------------------------------------------------
#define SC_NWG 64u
static __device__ __forceinline__ void dir_barrier(uint32_t* ctr) {
    __syncthreads();
    if (threadIdx.x == 0) {
        __threadfence();
        __hip_atomic_fetch_add(ctr, 1u, __ATOMIC_ACQ_REL, __HIP_MEMORY_SCOPE_AGENT);
        while (__hip_atomic_load(ctr, __ATOMIC_ACQUIRE, __HIP_MEMORY_SCOPE_AGENT) < SC_NWG)
            __builtin_amdgcn_s_sleep(2);
        __threadfence();
    }
    __syncthreads();
}

// ---------------------------------------------------------------------------
// Recurrent scan, one layer. grid = 128 WGs (d = blk>>6; 64 WG/dir), 256 thr.
// out stores: layer0 -> always bf16 staging at dout base; layer1 -> flag dtype.
// hn/cn: always flag dtype at element offsets 16777216 / 16908288 of dout.
// ---------------------------------------------------------------------------
#define HN_OFF ((size_t)16777216)
#define CN_OFF ((size_t)16908288)

__global__ __launch_bounds__(256, 1) void scan_kernel(
    const ushort_t* __restrict__ gx, const void* __restrict__ mask,
    const ushort_t* __restrict__ WhhT, const void* __restrict__ noiseh,
    ushort_t* __restrict__ hm, void* __restrict__ dout,
    uint32_t* __restrict__ bar, int layer, int out_use_flag,
    const uint32_t* __restrict__ flag)
{
    const uint32_t f32    = *flag;
    const uint32_t outf32 = out_use_flag ? f32 : 0u;
    const int d  = blockIdx.x >> 6;
    const int wg = blockIdx.x & 63;
    const int m0 = (wg >> 5) * 32;
    const int j0 = (wg & 31) * 16;
    const int tid = threadIdx.x;
    const int lane = tid & 63;
    const int w = tid >> 6;
    uint32_t* barv = bar + (size_t)(layer * 2 + d) * 257;
    int ep = 0;

    __shared__ ushort_t Wl[4 * 16 * 520];       // 66.56 KB
    __shared__ float gatesL[4][32][16];         // 8 KB

    // Load W_hh^T slice: 4 gates x 16 cols x 512 k
#pragma unroll
    for (int c = 0; c < 16; ++c) {
        int id = c * 256 + tid;
        int row = id >> 6;            // 0..63 = g*16+nn
        int kc  = (id & 63) * 8;
        int g = row >> 4, nn = row & 15;
        *(shortx8*)&Wl[(g * 16 + nn) * 520 + kc] =
            *(const shortx8*)&WhhT[(((size_t)d * 4 + g) * 512 + (j0 + nn)) * 512 + kc];
    }

    // Per-thread cells (2 each), persistent noise + state in registers
    int cb[2], cj[2];
    float nz[2][4];
    float hprev[2] = {0.f, 0.f}, cprev[2] = {0.f, 0.f};
#pragma unroll
    for (int cc = 0; cc < 2; ++cc) {
        int cell = tid + cc * 256;
        cb[cc] = m0 + (cell >> 4);
        cj[cc] = j0 + (cell & 15);
#pragma unroll
        for (int g = 0; g < 4; ++g)
            nz[cc][g] = loadf(noiseh, (((size_t)d * 4 + g) * 64 + cb[cc]) * 512 + cj[cc], f32);
        for (int p2 = 0; p2 < 2; ++p2)
            for (int g = 0; g < 4; ++g)
                hm[(size_t)((p2 * 2 + d) * 4 + g) * 32768 + (size_t)cb[cc] * 512 + cj[cc]] = 0;
    }
    dir_barrier(barv + (ep++));

    int pp = 0;
    const int mt_off = (w & 1) * 16;
    const int g0 = (w >> 1) * 2;
    const int arow = m0 + mt_off + (lane & 15);
    const int kb = (lane >> 4) * 8;

    for (int step = 0; step < 256; ++step) {
        const int t = (d == 0) ? step : (255 - step);

        // ---- MFMA: gates_partial = hm_g @ Whh_g  (this WG's rows/cols) ----
        floatx4 acc0 = (floatx4){0.f,0.f,0.f,0.f};
        floatx4 acc1 = (floatx4){0.f,0.f,0.f,0.f};
        const ushort_t* hmR = hm + (size_t)(pp * 2 + d) * 4 * 32768;
        const ushort_t* a0p = hmR + (size_t)(g0    ) * 32768 + (size_t)arow * 512 + kb;
        const ushort_t* a1p = hmR + (size_t)(g0 + 1) * 32768 + (size_t)arow * 512 + kb;
        const ushort_t* b0p = &Wl[((g0    ) * 16 + (lane & 15)) * 520 + kb];
        const ushort_t* b1p = &Wl[((g0 + 1) * 16 + (lane & 15)) * 520 + kb];
#pragma unroll
        for (int kt = 0; kt < 16; ++kt) {
            shortx8 a0 = *(const shortx8*)(a0p + kt * 32);
            shortx8 b0 = *(const shortx8*)(b0p + kt * 32);
            acc0 = __builtin_amdgcn_mfma_f32_16x16x32_bf16(a0, b0, acc0, 0, 0, 0);
            shortx8 a1 = *(const shortx8*)(a1p + kt * 32);
            shortx8 b1 = *(const shortx8*)(b1p + kt * 32);
            acc1 = __builtin_amdgcn_mfma_f32_16x16x32_bf16(a1, b1, acc1, 0, 0, 0);
        }
#pragma unroll
        for (int r = 0; r < 4; ++r) {
            gatesL[g0    ][mt_off + (lane >> 4) * 4 + r][lane & 15] = acc0[r];
            gatesL[g0 + 1][mt_off + (lane >> 4) * 4 + r][lane & 15] = acc1[r];
        }
        __syncthreads();

        // ---- cell update ----
        ushort_t* hmW = hm + (size_t)((pp ^ 1) * 2 + d) * 4 * 32768;
#pragma unroll
        for (int cc = 0; cc < 2; ++cc) {
            int b = cb[cc], j = cj[cc];
            int bl = b - m0, jl = j - j0;
            const ushort_t* gxp = gx + ((size_t)d * 16384 + (size_t)t * 64 + b) * 2048 + j;
            float p0 = gatesL[0][bl][jl] + bf2f(gxp[0]);
            float p1 = gatesL[1][bl][jl] + bf2f(gxp[512]);
            float p2 = gatesL[2][bl][jl] + bf2f(gxp[1024]);
            float p3 = gatesL[3][bl][jl] + bf2f(gxp[1536]);
            float ig = 1.f / (1.f + __expf(-p0));
            float fg = 1.f / (1.f + __expf(-p1));
            float gg = tanhf(p2);
            float og = 1.f / (1.f + __expf(-p3));
            float cnew = fg * cprev[cc] + ig * gg;
            float hnew = og * tanhf(cnew);
            float mt = loadf(mask, (size_t)t * 64 + b, f32);
            float hv = hnew * mt + hprev[cc] * (1.f - mt);
            float cv = cnew * mt + cprev[cc] * (1.f - mt);
            hprev[cc] = hv; cprev[cc] = cv;
            size_t oo = ((size_t)t * 64 + b) * 1024 + (size_t)d * 512 + j;
            if (outf32) ((float*)dout)[oo] = hv;
            else        ((ushort_t*)dout)[oo] = f2bf(hv);
#pragma unroll
            for (int g = 0; g < 4; ++g)
                hmW[(size_t)g * 32768 + (size_t)b * 512 + j] = f2bf(hv * nz[cc][g]);
        }
        dir_barrier(barv + (ep++));
        pp ^= 1;
    }

    const int slot = layer * 2 + d;
#pragma unroll
    for (int cc = 0; cc < 2; ++cc) {
        size_t ho = HN_OFF + ((size_t)slot * 64 + cb[cc]) * 512 + cj[cc];
        size_t co = CN_OFF + ((size_t)slot * 64 + cb[cc]) * 512 + cj[cc];
        if (f32) { ((float*)dout)[ho] = hprev[cc]; ((float*)dout)[co] = cprev[cc]; }
        else     { ((ushort_t*)dout)[ho] = f2bf(hprev[cc]); ((ushort_t*)dout)[co] = f2bf(cprev[cc]); }
    }
}

// ---------------------------------------------------------------------------
// Workspace layout (bytes) — total 148,922,368 (~142 MB)
// ---------------------------------------------------------------------------
#define OFF_WIH   ((size_t)0)           // W_ih^T bf16: 8,388,608 (max of layers)
#define OFF_WHH   ((size_t)8388608)     // W_hh^T bf16: 4,194,304
#define OFF_BS    ((size_t)12582912)    // bias f32:    16,384
#define OFF_BAR   ((size_t)12599296)    // barriers:     6,144
#define OFF_FLAG  ((size_t)12605440)    // dtype flag:     256
#define OFF_HM    ((size_t)12607488)    // h*noise ping-pong: 2,097,152
#define OFF_GX    ((size_t)14704640)    // gx bf16: 134,217,728

extern "C" void kernel_launch(void* const* d_in, const int* in_sizes, int n_in,
                              void* d_out, int out_size, void* d_ws, size_t ws_size,
                              hipStream_t stream) {
    const void* x        = d_in[0];
    const void* mask     = d_in[1];
    const void* w_ih_l0  = d_in[2];
    const void* w_hh_l0  = d_in[3];
    const void* b_ih_l0  = d_in[4];
    const void* b_hh_l0  = d_in[5];
    const void* n_in_l0  = d_in[6];
    const void* n_hid_l0 = d_in[7];
    const void* w_ih_l1  = d_in[8];
    const void* w_hh_l1  = d_in[9];
    const void* b_ih_l1  = d_in[10];
    const void* b_hh_l1  = d_in[11];
    const void* n_in_l1  = d_in[12];
    const void* n_hid_l1 = d_in[13];

    char* ws = (char*)d_ws;
    ushort_t* WIH  = (ushort_t*)(ws + OFF_WIH);
    ushort_t* WHH  = (ushort_t*)(ws + OFF_WHH);
    float*    BS   = (float*)(ws + OFF_BS);
    uint32_t* BAR  = (uint32_t*)(ws + OFF_BAR);
    uint32_t* FLAG = (uint32_t*)(ws + OFF_FLAG);
    ushort_t* HM   = (ushort_t*)(ws + OFF_HM);
    ushort_t* GX   = (ushort_t*)(ws + OFF_GX);

    hipMemsetAsync(BAR, 0, 6144 + 256, stream);   // barriers + flag
    detect_dtype<<<1, 256, 0, stream>>>((const ushort_t*)x, FLAG);

    // ---- layer 0 (layer-0 output staged bf16 at d_out base) ----------------
    transpose_k<<<dim3(8, 8, 8),  256, 0, stream>>>(w_ih_l0, WIH, 512, 512, FLAG);
    transpose_k<<<dim3(8, 8, 8),  256, 0, stream>>>(w_hh_l0, WHH, 512, 512, FLAG);
    bias_kernel<<<16, 256, 0, stream>>>(b_ih_l0, b_hh_l0, BS, FLAG);
    gx_gemm<<<dim3(4, 128, 8), 256, 0, stream>>>(x, n_in_l0, WIH, BS, GX, 512, FLAG, 1);
    scan_kernel<<<dim3(128), 256, 0, stream>>>(GX, mask, WHH, n_hid_l0, HM, d_out, BAR, 0, 0, FLAG);

    // ---- layer 1 (gemm consumes bf16 staging, then scan writes final) ------
    transpose_k<<<dim3(8, 16, 8), 256, 0, stream>>>(w_ih_l1, WIH, 1024, 512, FLAG);
    transpose_k<<<dim3(8, 8, 8),  256, 0, stream>>>(w_hh_l1, WHH, 512, 512, FLAG);
    bias_kernel<<<16, 256, 0, stream>>>(b_ih_l1, b_hh_l1, BS, FLAG);
    gx_gemm<<<dim3(4, 128, 8), 256, 0, stream>>>(d_out, n_in_l1, WIH, BS, GX, 1024, FLAG, 0);
    scan_kernel<<<dim3(128), 256, 0, stream>>>(GX, mask, WHH, n_hid_l1, HM, d_out, BAR, 1, 1, FLAG);
}

// Round 4
// 4669.981 us; speedup vs baseline: 2.1531x; 2.1531x over previous
//
#include <hip/hip_runtime.h>
#include <hip/hip_bf16.h>
#include <stdint.h>

typedef unsigned short ushort_t;
typedef __attribute__((ext_vector_type(4))) float  floatx4;
typedef __attribute__((ext_vector_type(8))) short  shortx8;

static __device__ __forceinline__ float bf2f(ushort_t u) {
    uint32_t x = ((uint32_t)u) << 16;
    return __builtin_bit_cast(float, x);
}
static __device__ __forceinline__ ushort_t f2bf(float f) {
    uint32_t x = __builtin_bit_cast(uint32_t, f);
    uint32_t r = (x + 0x7fffu + ((x >> 16) & 1u)) >> 16;
    return (ushort_t)r;
}
// dtype-branched scalar load (flag uniform -> no divergence)
static __device__ __forceinline__ float loadf(const void* p, size_t i, uint32_t f32) {
    return f32 ? ((const float*)p)[i] : bf2f(((const ushort_t*)p)[i]);
}
// dtype-branched 8-element load (i multiple of 8 -> aligned vector loads)
static __device__ __forceinline__ void load8f(const void* p, size_t i, uint32_t f32, float* o) {
    if (f32) {
        float4 a = *(const float4*)((const float*)p + i);
        float4 b = *(const float4*)((const float*)p + i + 4);
        o[0]=a.x; o[1]=a.y; o[2]=a.z; o[3]=a.w; o[4]=b.x; o[5]=b.y; o[6]=b.z; o[7]=b.w;
    } else {
        shortx8 v = *(const shortx8*)((const ushort_t*)p + i);
#pragma unroll
        for (int e = 0; e < 8; ++e) o[e] = bf2f((ushort_t)v[e]);
    }
}

// ---------------------------------------------------------------------------
// Detect input dtype from x's bit patterns (fp32 vs bf16).
// ---------------------------------------------------------------------------
__global__ __launch_bounds__(256) void detect_dtype(
    const ushort_t* __restrict__ x, uint32_t* __restrict__ flag)
{
    const int tid = threadIdx.x;
    uint32_t bad = 0;
    for (int i = tid; i < 16384; i += 256) {
        uint32_t e = (x[i] >> 7) & 0xFFu;
        if (e >= 0xFFu || (e > 0u && e < 100u)) bad++;
    }
    __shared__ uint32_t s[256];
    s[tid] = bad; __syncthreads();
    for (int st = 128; st > 0; st >>= 1) {
        if (tid < st) s[tid] += s[tid + st];
        __syncthreads();
    }
    if (tid == 0) *flag = (s[0] > 1024u) ? 1u : 0u;
}

// ---------------------------------------------------------------------------
// Prep: tiled transpose  src[slice][K][N] -> dst[slice][N][K]  (dst bf16 in ws)
// ---------------------------------------------------------------------------
__global__ __launch_bounds__(256) void transpose_k(
    const void* __restrict__ src, ushort_t* __restrict__ dst, int K, int N,
    const uint32_t* __restrict__ flag)
{
    const uint32_t f32 = *flag;
    __shared__ ushort_t tile[64][72];
    const size_t so = (size_t)blockIdx.z * (size_t)K * (size_t)N;
    const int k0 = blockIdx.y * 64, n0 = blockIdx.x * 64;
    const int r = threadIdx.x >> 2;
    const int cseg = (threadIdx.x & 3) * 16;
#pragma unroll
    for (int c = 0; c < 16; c += 8) {
        float t8[8];
        load8f(src, so + (size_t)(k0 + r) * N + (n0 + cseg + c), f32, t8);
        shortx8 v;
#pragma unroll
        for (int e = 0; e < 8; ++e) v[e] = (short)f2bf(t8[e]);
        *(shortx8*)&tile[r][cseg + c] = v;
    }
    __syncthreads();
#pragma unroll
    for (int c = 0; c < 16; c += 8) {
        shortx8 v;
#pragma unroll
        for (int i = 0; i < 8; ++i) v[i] = (short)tile[cseg + c + i][r];
        *(shortx8*)&dst[so + (size_t)(n0 + r) * K + (k0 + cseg + c)] = v;
    }
}

// ---------------------------------------------------------------------------
// Prep: bias sums (fp32): bs[dg*512+h] = b_ih + b_hh   (one layer, 4096 elems)
// ---------------------------------------------------------------------------
__global__ __launch_bounds__(256) void bias_kernel(
    const void* __restrict__ bih, const void* __restrict__ bhh,
    float* __restrict__ bs, const uint32_t* __restrict__ flag)
{
    const uint32_t f32 = *flag;
    int i = blockIdx.x * 256 + threadIdx.x;   // 0..4095
    bs[i] = loadf(bih, i, f32) + loadf(bhh, i, f32);
}

// ---------------------------------------------------------------------------
// gx GEMM:  gx[d][t*64+b][g][h] = (X[row,:] * noise[d,g,b,:]) @ W[d,g] + bias
//   grid: (4, 128, 8)   block 256
// ---------------------------------------------------------------------------
__global__ __launch_bounds__(256, 2) void gx_gemm(
    const void* __restrict__ X, const void* __restrict__ noise,
    const ushort_t* __restrict__ WT, const float* __restrict__ bsum,
    ushort_t* __restrict__ gxout, int K,
    const uint32_t* __restrict__ flag, int x_use_flag)
{
    const uint32_t f32  = *flag;
    const uint32_t xf32 = x_use_flag ? f32 : 0u;
    const int dg  = blockIdx.z;
    const int n0  = blockIdx.x * 128;
    const int m0t = blockIdx.y * 128;
    const int tid = threadIdx.x;
    const int lane = tid & 63;
    const int w    = tid >> 6;
    const int wm = (w & 1) * 64, wn = (w >> 1) * 64;

    __shared__ ushort_t As[128][72];
    __shared__ ushort_t Bs[128][72];

    floatx4 acc[4][4];
#pragma unroll
    for (int i = 0; i < 4; ++i)
#pragma unroll
        for (int j = 0; j < 4; ++j) acc[i][j] = (floatx4){0.f, 0.f, 0.f, 0.f};

    const ushort_t* Wp = WT + (size_t)dg * 512 * K + (size_t)n0 * K;

    for (int k0 = 0; k0 < K; k0 += 64) {
#pragma unroll
        for (int c = 0; c < 4; ++c) {
            int id  = c * 256 + tid;
            int row = id >> 3;
            int kc  = (id & 7) * 8;
            int grow = m0t + row;
            float xv[8], nv[8];
            load8f(X, (size_t)grow * K + k0 + kc, xf32, xv);
            load8f(noise, ((size_t)dg * 64 + (grow & 63)) * K + k0 + kc, f32, nv);
            shortx8 av;
#pragma unroll
            for (int e = 0; e < 8; ++e) av[e] = (short)f2bf(xv[e] * nv[e]);
            *(shortx8*)&As[row][kc] = av;
            *(shortx8*)&Bs[row][kc] = *(const shortx8*)(Wp + (size_t)row * K + k0 + kc);
        }
        __syncthreads();
#pragma unroll
        for (int ks = 0; ks < 2; ++ks) {
            int kb = ks * 32 + (lane >> 4) * 8;
            shortx8 af[4], bfr[4];
#pragma unroll
            for (int i = 0; i < 4; ++i) af[i]  = *(const shortx8*)&As[wm + i * 16 + (lane & 15)][kb];
#pragma unroll
            for (int j = 0; j < 4; ++j) bfr[j] = *(const shortx8*)&Bs[wn + j * 16 + (lane & 15)][kb];
#pragma unroll
            for (int i = 0; i < 4; ++i)
#pragma unroll
                for (int j = 0; j < 4; ++j)
                    acc[i][j] = __builtin_amdgcn_mfma_f32_16x16x32_bf16(af[i], bfr[j], acc[i][j], 0, 0, 0);
        }
        __syncthreads();
    }

    const int d = dg >> 2, g = dg & 3;
#pragma unroll
    for (int i = 0; i < 4; ++i) {
        int rowb = m0t + wm + i * 16 + (lane >> 4) * 4;
#pragma unroll
        for (int j = 0; j < 4; ++j) {
            int col = n0 + wn + j * 16 + (lane & 15);
            float bv = bsum[dg * 512 + col];
#pragma unroll
            for (int r = 0; r < 4; ++r) {
                size_t orow = (size_t)(rowb + r);
                gxout[((size_t)d * 16384 + orow) * 2048 + (size_t)g * 512 + col] =
                    f2bf(acc[i][j][r] + bv);
            }
        }
    }
}

// ---------------------------------------------------------------------------
// Flag-array barrier over a 32-WG domain. Each WG publishes a monotonic
// episode value (relaxed agent store, sc1 write-through, no RMW). Wave 0
// polls the 32 flags with relaxed loads (no per-iteration L2 invalidate).
// One acquire fence per step after release makes subsequent normal loads
// coherent (single buffer_inv).
// ---------------------------------------------------------------------------
static __device__ __forceinline__ void domain_barrier(
    uint32_t* flags, int wgin, uint32_t ep)
{
    __syncthreads();    // drains each wave's vmem (incl. sc1 hm stores) before arrival
    if (threadIdx.x == 0)
        __hip_atomic_store(flags + wgin, ep, __ATOMIC_RELAXED, __HIP_MEMORY_SCOPE_AGENT);
    if (threadIdx.x < 64) {
        const int l = threadIdx.x;
        while (true) {
            uint32_t v = (l < 32)
                ? __hip_atomic_load(flags + l, __ATOMIC_RELAXED, __HIP_MEMORY_SCOPE_AGENT)
                : ep;
            if (__ballot(v < ep) == 0ull) break;
            __builtin_amdgcn_s_sleep(1);
        }
    }
    __syncthreads();
    __builtin_amdgcn_fence(__ATOMIC_ACQUIRE, "agent");
}

// ---------------------------------------------------------------------------
// Recurrent scan, one layer. grid = 128 WGs (d = blk>>6; 64 WG/dir), 256 thr.
// Sync domains: (dir, m0-half) -> 4 independent groups of 32 WGs (batch rows
// are independent chains; only hidden dim k couples WGs sharing m0).
// ---------------------------------------------------------------------------
#define HN_OFF ((size_t)16777216)
#define CN_OFF ((size_t)16908288)

__global__ __launch_bounds__(256, 1) void scan_kernel(
    const ushort_t* __restrict__ gx, const void* __restrict__ mask,
    const ushort_t* __restrict__ WhhT, const void* __restrict__ noiseh,
    ushort_t* __restrict__ hm, void* __restrict__ dout,
    uint32_t* __restrict__ bar, int layer, int out_use_flag,
    const uint32_t* __restrict__ flag)
{
    const uint32_t f32    = *flag;
    const uint32_t outf32 = out_use_flag ? f32 : 0u;
    const int d  = blockIdx.x >> 6;
    const int wg = blockIdx.x & 63;
    const int m0 = (wg >> 5) * 32;
    const int j0 = (wg & 31) * 16;
    const int tid = threadIdx.x;
    const int lane = tid & 63;
    const int w = tid >> 6;
    const int dom  = d * 2 + (wg >> 5);
    const int wgin = wg & 31;
    uint32_t* flags = bar + (size_t)(layer * 4 + dom) * 64;

    __shared__ ushort_t Wl[4 * 16 * 520];       // 66.56 KB
    __shared__ float gatesL[4][32][16];         // 8 KB

    // Load W_hh^T slice: 4 gates x 16 cols x 512 k
#pragma unroll
    for (int c = 0; c < 16; ++c) {
        int id = c * 256 + tid;
        int row = id >> 6;            // 0..63 = g*16+nn
        int kc  = (id & 63) * 8;
        int g = row >> 4, nn = row & 15;
        *(shortx8*)&Wl[(g * 16 + nn) * 520 + kc] =
            *(const shortx8*)&WhhT[(((size_t)d * 4 + g) * 512 + (j0 + nn)) * 512 + kc];
    }

    // Per-thread cells (2 each), persistent noise + state in registers
    int cb[2], cj[2];
    float nz[2][4];
    float hprev[2] = {0.f, 0.f}, cprev[2] = {0.f, 0.f};
#pragma unroll
    for (int cc = 0; cc < 2; ++cc) {
        int cell = tid + cc * 256;
        cb[cc] = m0 + (cell >> 4);
        cj[cc] = j0 + (cell & 15);
#pragma unroll
        for (int g = 0; g < 4; ++g)
            nz[cc][g] = loadf(noiseh, (((size_t)d * 4 + g) * 64 + cb[cc]) * 512 + cj[cc], f32);
        // zero BOTH ping-pong hm slots (sc1 write-through, paired u32)
        if ((tid & 1) == 0) {
            for (int p2 = 0; p2 < 2; ++p2)
#pragma unroll
                for (int g = 0; g < 4; ++g)
                    __hip_atomic_store(
                        (uint32_t*)(hm + (size_t)((p2 * 2 + d) * 4 + g) * 32768
                                       + (size_t)cb[cc] * 512 + cj[cc]),
                        0u, __ATOMIC_RELAXED, __HIP_MEMORY_SCOPE_AGENT);
        }
    }

    // gx/mask prefetch registers
    ushort_t gpre[2][4];
    float    mpre[2];
    auto ldpre = [&](int tt) {
#pragma unroll
        for (int cc = 0; cc < 2; ++cc) {
            const ushort_t* gxp = gx + ((size_t)d * 16384 + (size_t)tt * 64 + cb[cc]) * 2048 + cj[cc];
            gpre[cc][0] = gxp[0];
            gpre[cc][1] = gxp[512];
            gpre[cc][2] = gxp[1024];
            gpre[cc][3] = gxp[1536];
            mpre[cc] = loadf(mask, (size_t)tt * 64 + cb[cc], f32);
        }
    };
    ldpre(d == 0 ? 0 : 255);

    domain_barrier(flags, wgin, 1u);

    int pp = 0;
    const int mt_off = (w & 1) * 16;
    const int g0 = (w >> 1) * 2;
    const int arow = m0 + mt_off + (lane & 15);
    const int kb = (lane >> 4) * 8;

    for (int step = 0; step < 256; ++step) {
        const int t = (d == 0) ? step : (255 - step);

        // ---- MFMA: gates_partial = hm_g @ Whh_g  (this WG's rows/cols) ----
        floatx4 acc0 = (floatx4){0.f,0.f,0.f,0.f};
        floatx4 acc1 = (floatx4){0.f,0.f,0.f,0.f};
        const ushort_t* hmR = hm + (size_t)(pp * 2 + d) * 4 * 32768;
        const ushort_t* a0p = hmR + (size_t)(g0    ) * 32768 + (size_t)arow * 512 + kb;
        const ushort_t* a1p = hmR + (size_t)(g0 + 1) * 32768 + (size_t)arow * 512 + kb;
        const ushort_t* b0p = &Wl[((g0    ) * 16 + (lane & 15)) * 520 + kb];
        const ushort_t* b1p = &Wl[((g0 + 1) * 16 + (lane & 15)) * 520 + kb];
#pragma unroll
        for (int kt = 0; kt < 16; ++kt) {
            shortx8 a0 = *(const shortx8*)(a0p + kt * 32);
            shortx8 b0 = *(const shortx8*)(b0p + kt * 32);
            acc0 = __builtin_amdgcn_mfma_f32_16x16x32_bf16(a0, b0, acc0, 0, 0, 0);
            shortx8 a1 = *(const shortx8*)(a1p + kt * 32);
            shortx8 b1 = *(const shortx8*)(b1p + kt * 32);
            acc1 = __builtin_amdgcn_mfma_f32_16x16x32_bf16(a1, b1, acc1, 0, 0, 0);
        }
#pragma unroll
        for (int r = 0; r < 4; ++r) {
            gatesL[g0    ][mt_off + (lane >> 4) * 4 + r][lane & 15] = acc0[r];
            gatesL[g0 + 1][mt_off + (lane >> 4) * 4 + r][lane & 15] = acc1[r];
        }
        __syncthreads();

        // ---- cell update ----
        ushort_t* hmW = hm + (size_t)((pp ^ 1) * 2 + d) * 4 * 32768;
#pragma unroll
        for (int cc = 0; cc < 2; ++cc) {
            int b = cb[cc], j = cj[cc];
            int bl = b - m0, jl = j - j0;
            float p0 = gatesL[0][bl][jl] + bf2f(gpre[cc][0]);
            float p1 = gatesL[1][bl][jl] + bf2f(gpre[cc][1]);
            float p2 = gatesL[2][bl][jl] + bf2f(gpre[cc][2]);
            float p3 = gatesL[3][bl][jl] + bf2f(gpre[cc][3]);
            float ig = 1.f / (1.f + __expf(-p0));
            float fg = 1.f / (1.f + __expf(-p1));
            float gg = tanhf(p2);
            float og = 1.f / (1.f + __expf(-p3));
            float cnew = fg * cprev[cc] + ig * gg;
            float hnew = og * tanhf(cnew);
            float mt = mpre[cc];
            float hv = hnew * mt + hprev[cc] * (1.f - mt);
            float cv = cnew * mt + cprev[cc] * (1.f - mt);
            hprev[cc] = hv; cprev[cc] = cv;
            size_t oo = ((size_t)t * 64 + b) * 1024 + (size_t)d * 512 + j;
            if (outf32) ((float*)dout)[oo] = hv;
            else        ((ushort_t*)dout)[oo] = f2bf(hv);
            // hm: paired u32 sc1 write-through stores (adjacent j in one word)
#pragma unroll
            for (int g = 0; g < 4; ++g) {
                uint32_t own = (uint32_t)f2bf(hv * nz[cc][g]);
                uint32_t oth = (uint32_t)__shfl_xor((int)own, 1, 64);
                if ((tid & 1) == 0) {
                    uint32_t word = (own & 0xffffu) | (oth << 16);
                    __hip_atomic_store(
                        (uint32_t*)(hmW + (size_t)g * 32768 + (size_t)b * 512 + j),
                        word, __ATOMIC_RELAXED, __HIP_MEMORY_SCOPE_AGENT);
                }
            }
        }
        // prefetch next step's gx+mask; latency hides under the barrier
        if (step < 255) ldpre(d == 0 ? step + 1 : 254 - step);

        domain_barrier(flags, wgin, (uint32_t)(step + 2));
        pp ^= 1;
    }

    const int slot = layer * 2 + d;
#pragma unroll
    for (int cc = 0; cc < 2; ++cc) {
        size_t ho = HN_OFF + ((size_t)slot * 64 + cb[cc]) * 512 + cj[cc];
        size_t co = CN_OFF + ((size_t)slot * 64 + cb[cc]) * 512 + cj[cc];
        if (f32) { ((float*)dout)[ho] = hprev[cc]; ((float*)dout)[co] = cprev[cc]; }
        else     { ((ushort_t*)dout)[ho] = f2bf(hprev[cc]); ((ushort_t*)dout)[co] = f2bf(cprev[cc]); }
    }
}

// ---------------------------------------------------------------------------
// Workspace layout (bytes) — total ~142 MB
// ---------------------------------------------------------------------------
#define OFF_WIH   ((size_t)0)           // W_ih^T bf16: 8,388,608 (max of layers)
#define OFF_WHH   ((size_t)8388608)     // W_hh^T bf16: 4,194,304
#define OFF_BS    ((size_t)12582912)    // bias f32:    16,384
#define OFF_BAR   ((size_t)12599296)    // barrier flags: 6,144 (2048 used)
#define OFF_FLAG  ((size_t)12605440)    // dtype flag:     256
#define OFF_HM    ((size_t)12607488)    // h*noise ping-pong: 2,097,152
#define OFF_GX    ((size_t)14704640)    // gx bf16: 134,217,728

extern "C" void kernel_launch(void* const* d_in, const int* in_sizes, int n_in,
                              void* d_out, int out_size, void* d_ws, size_t ws_size,
                              hipStream_t stream) {
    const void* x        = d_in[0];
    const void* mask     = d_in[1];
    const void* w_ih_l0  = d_in[2];
    const void* w_hh_l0  = d_in[3];
    const void* b_ih_l0  = d_in[4];
    const void* b_hh_l0  = d_in[5];
    const void* n_in_l0  = d_in[6];
    const void* n_hid_l0 = d_in[7];
    const void* w_ih_l1  = d_in[8];
    const void* w_hh_l1  = d_in[9];
    const void* b_ih_l1  = d_in[10];
    const void* b_hh_l1  = d_in[11];
    const void* n_in_l1  = d_in[12];
    const void* n_hid_l1 = d_in[13];

    char* ws = (char*)d_ws;
    ushort_t* WIH  = (ushort_t*)(ws + OFF_WIH);
    ushort_t* WHH  = (ushort_t*)(ws + OFF_WHH);
    float*    BS   = (float*)(ws + OFF_BS);
    uint32_t* BAR  = (uint32_t*)(ws + OFF_BAR);
    uint32_t* FLAG = (uint32_t*)(ws + OFF_FLAG);
    ushort_t* HM   = (ushort_t*)(ws + OFF_HM);
    ushort_t* GX   = (ushort_t*)(ws + OFF_GX);

    hipMemsetAsync(BAR, 0, 6144 + 256, stream);   // barrier flags + dtype flag
    detect_dtype<<<1, 256, 0, stream>>>((const ushort_t*)x, FLAG);

    // ---- layer 0 (layer-0 output staged bf16 at d_out base) ----------------
    transpose_k<<<dim3(8, 8, 8),  256, 0, stream>>>(w_ih_l0, WIH, 512, 512, FLAG);
    transpose_k<<<dim3(8, 8, 8),  256, 0, stream>>>(w_hh_l0, WHH, 512, 512, FLAG);
    bias_kernel<<<16, 256, 0, stream>>>(b_ih_l0, b_hh_l0, BS, FLAG);
    gx_gemm<<<dim3(4, 128, 8), 256, 0, stream>>>(x, n_in_l0, WIH, BS, GX, 512, FLAG, 1);
    scan_kernel<<<dim3(128), 256, 0, stream>>>(GX, mask, WHH, n_hid_l0, HM, d_out, BAR, 0, 0, FLAG);

    // ---- layer 1 (gemm consumes bf16 staging, then scan writes final) ------
    transpose_k<<<dim3(8, 16, 8), 256, 0, stream>>>(w_ih_l1, WIH, 1024, 512, FLAG);
    transpose_k<<<dim3(8, 8, 8),  256, 0, stream>>>(w_hh_l1, WHH, 512, 512, FLAG);
    bias_kernel<<<16, 256, 0, stream>>>(b_ih_l1, b_hh_l1, BS, FLAG);
    gx_gemm<<<dim3(4, 128, 8), 256, 0, stream>>>(d_out, n_in_l1, WIH, BS, GX, 1024, FLAG, 0);
    scan_kernel<<<dim3(128), 256, 0, stream>>>(GX, mask, WHH, n_hid_l1, HM, d_out, BAR, 1, 1, FLAG);
}

// Round 5
// 4419.240 us; speedup vs baseline: 2.2753x; 1.0567x over previous
//
#include <hip/hip_runtime.h>
#include <hip/hip_bf16.h>
#include <stdint.h>

typedef unsigned short ushort_t;
typedef __attribute__((ext_vector_type(4))) float  floatx4;
typedef __attribute__((ext_vector_type(8))) short  shortx8;

static __device__ __forceinline__ float bf2f(ushort_t u) {
    uint32_t x = ((uint32_t)u) << 16;
    return __builtin_bit_cast(float, x);
}
static __device__ __forceinline__ ushort_t f2bf(float f) {
    uint32_t x = __builtin_bit_cast(uint32_t, f);
    uint32_t r = (x + 0x7fffu + ((x >> 16) & 1u)) >> 16;
    return (ushort_t)r;
}
// dtype-branched scalar load (flag uniform -> no divergence)
static __device__ __forceinline__ float loadf(const void* p, size_t i, uint32_t f32) {
    return f32 ? ((const float*)p)[i] : bf2f(((const ushort_t*)p)[i]);
}
// dtype-branched 8-element load (i multiple of 8 -> aligned vector loads)
static __device__ __forceinline__ void load8f(const void* p, size_t i, uint32_t f32, float* o) {
    if (f32) {
        float4 a = *(const float4*)((const float*)p + i);
        float4 b = *(const float4*)((const float*)p + i + 4);
        o[0]=a.x; o[1]=a.y; o[2]=a.z; o[3]=a.w; o[4]=b.x; o[5]=b.y; o[6]=b.z; o[7]=b.w;
    } else {
        shortx8 v = *(const shortx8*)((const ushort_t*)p + i);
#pragma unroll
        for (int e = 0; e < 8; ++e) o[e] = bf2f((ushort_t)v[e]);
    }
}

// ---------------------------------------------------------------------------
// Detect input dtype from x's bit patterns (fp32 vs bf16).
// ---------------------------------------------------------------------------
__global__ __launch_bounds__(256) void detect_dtype(
    const ushort_t* __restrict__ x, uint32_t* __restrict__ flag)
{
    const int tid = threadIdx.x;
    uint32_t bad = 0;
    for (int i = tid; i < 16384; i += 256) {
        uint32_t e = (x[i] >> 7) & 0xFFu;
        if (e >= 0xFFu || (e > 0u && e < 100u)) bad++;
    }
    __shared__ uint32_t s[256];
    s[tid] = bad; __syncthreads();
    for (int st = 128; st > 0; st >>= 1) {
        if (tid < st) s[tid] += s[tid + st];
        __syncthreads();
    }
    if (tid == 0) *flag = (s[0] > 1024u) ? 1u : 0u;
}

// ---------------------------------------------------------------------------
// Prep: tiled transpose  src[slice][K][N] -> dst[slice][N][K]  (dst bf16 in ws)
// ---------------------------------------------------------------------------
__global__ __launch_bounds__(256) void transpose_k(
    const void* __restrict__ src, ushort_t* __restrict__ dst, int K, int N,
    const uint32_t* __restrict__ flag)
{
    const uint32_t f32 = *flag;
    __shared__ ushort_t tile[64][72];
    const size_t so = (size_t)blockIdx.z * (size_t)K * (size_t)N;
    const int k0 = blockIdx.y * 64, n0 = blockIdx.x * 64;
    const int r = threadIdx.x >> 2;
    const int cseg = (threadIdx.x & 3) * 16;
#pragma unroll
    for (int c = 0; c < 16; c += 8) {
        float t8[8];
        load8f(src, so + (size_t)(k0 + r) * N + (n0 + cseg + c), f32, t8);
        shortx8 v;
#pragma unroll
        for (int e = 0; e < 8; ++e) v[e] = (short)f2bf(t8[e]);
        *(shortx8*)&tile[r][cseg + c] = v;
    }
    __syncthreads();
#pragma unroll
    for (int c = 0; c < 16; c += 8) {
        shortx8 v;
#pragma unroll
        for (int i = 0; i < 8; ++i) v[i] = (short)tile[cseg + c + i][r];
        *(shortx8*)&dst[so + (size_t)(n0 + r) * K + (k0 + cseg + c)] = v;
    }
}

// ---------------------------------------------------------------------------
// Prep: bias sums (fp32): bs[dg*512+h] = b_ih + b_hh   (one layer, 4096 elems)
// ---------------------------------------------------------------------------
__global__ __launch_bounds__(256) void bias_kernel(
    const void* __restrict__ bih, const void* __restrict__ bhh,
    float* __restrict__ bs, const uint32_t* __restrict__ flag)
{
    const uint32_t f32 = *flag;
    int i = blockIdx.x * 256 + threadIdx.x;   // 0..4095
    bs[i] = loadf(bih, i, f32) + loadf(bhh, i, f32);
}

// ---------------------------------------------------------------------------
// gx GEMM:  gx[d][t*64+b][g][h] = (X[row,:] * noise[d,g,b,:]) @ W[d,g] + bias
//   grid: (4, 128, 8)   block 256
// ---------------------------------------------------------------------------
__global__ __launch_bounds__(256, 2) void gx_gemm(
    const void* __restrict__ X, const void* __restrict__ noise,
    const ushort_t* __restrict__ WT, const float* __restrict__ bsum,
    ushort_t* __restrict__ gxout, int K,
    const uint32_t* __restrict__ flag, int x_use_flag)
{
    const uint32_t f32  = *flag;
    const uint32_t xf32 = x_use_flag ? f32 : 0u;
    const int dg  = blockIdx.z;
    const int n0  = blockIdx.x * 128;
    const int m0t = blockIdx.y * 128;
    const int tid = threadIdx.x;
    const int lane = tid & 63;
    const int w    = tid >> 6;
    const int wm = (w & 1) * 64, wn = (w >> 1) * 64;

    __shared__ ushort_t As[128][72];
    __shared__ ushort_t Bs[128][72];

    floatx4 acc[4][4];
#pragma unroll
    for (int i = 0; i < 4; ++i)
#pragma unroll
        for (int j = 0; j < 4; ++j) acc[i][j] = (floatx4){0.f, 0.f, 0.f, 0.f};

    const ushort_t* Wp = WT + (size_t)dg * 512 * K + (size_t)n0 * K;

    for (int k0 = 0; k0 < K; k0 += 64) {
#pragma unroll
        for (int c = 0; c < 4; ++c) {
            int id  = c * 256 + tid;
            int row = id >> 3;
            int kc  = (id & 7) * 8;
            int grow = m0t + row;
            float xv[8], nv[8];
            load8f(X, (size_t)grow * K + k0 + kc, xf32, xv);
            load8f(noise, ((size_t)dg * 64 + (grow & 63)) * K + k0 + kc, f32, nv);
            shortx8 av;
#pragma unroll
            for (int e = 0; e < 8; ++e) av[e] = (short)f2bf(xv[e] * nv[e]);
            *(shortx8*)&As[row][kc] = av;
            *(shortx8*)&Bs[row][kc] = *(const shortx8*)(Wp + (size_t)row * K + k0 + kc);
        }
        __syncthreads();
#pragma unroll
        for (int ks = 0; ks < 2; ++ks) {
            int kb = ks * 32 + (lane >> 4) * 8;
            shortx8 af[4], bfr[4];
#pragma unroll
            for (int i = 0; i < 4; ++i) af[i]  = *(const shortx8*)&As[wm + i * 16 + (lane & 15)][kb];
#pragma unroll
            for (int j = 0; j < 4; ++j) bfr[j] = *(const shortx8*)&Bs[wn + j * 16 + (lane & 15)][kb];
#pragma unroll
            for (int i = 0; i < 4; ++i)
#pragma unroll
                for (int j = 0; j < 4; ++j)
                    acc[i][j] = __builtin_amdgcn_mfma_f32_16x16x32_bf16(af[i], bfr[j], acc[i][j], 0, 0, 0);
        }
        __syncthreads();
    }

    const int d = dg >> 2, g = dg & 3;
#pragma unroll
    for (int i = 0; i < 4; ++i) {
        int rowb = m0t + wm + i * 16 + (lane >> 4) * 4;
#pragma unroll
        for (int j = 0; j < 4; ++j) {
            int col = n0 + wn + j * 16 + (lane & 15);
            float bv = bsum[dg * 512 + col];
#pragma unroll
            for (int r = 0; r < 4; ++r) {
                size_t orow = (size_t)(rowb + r);
                gxout[((size_t)d * 16384 + orow) * 2048 + (size_t)g * 512 + col] =
                    f2bf(acc[i][j][r] + bv);
            }
        }
    }
}

// ---------------------------------------------------------------------------
// Flag-array barrier over a 32-WG domain. One flag per WG, ONE CACHELINE per
// flag (stride 16 dwords) so arrivals/polls spread across MALL slices.
// Monotonic episode values; relaxed agent ops (no per-poll L2 invalidate);
// one acquire fence per step after exit.
// ---------------------------------------------------------------------------
static __device__ __forceinline__ void domain_barrier(
    uint32_t* flags, int wgin, uint32_t ep)
{
    __syncthreads();    // drains each wave's vmem (incl. sc1 hm stores) before arrival
    if (threadIdx.x == 0)
        __hip_atomic_store(flags + (size_t)wgin * 16, ep, __ATOMIC_RELAXED, __HIP_MEMORY_SCOPE_AGENT);
    if (threadIdx.x < 64) {
        const int l = threadIdx.x;
        while (true) {
            uint32_t v = (l < 32)
                ? __hip_atomic_load(flags + (size_t)l * 16, __ATOMIC_RELAXED, __HIP_MEMORY_SCOPE_AGENT)
                : ep;
            if (__ballot(v < ep) == 0ull) break;
            __builtin_amdgcn_s_sleep(1);
        }
    }
    __syncthreads();
    __builtin_amdgcn_fence(__ATOMIC_ACQUIRE, "agent");
}

// ---------------------------------------------------------------------------
// Recurrent scan, one layer. grid = 128 WGs (d = blk>>6; 64 WG/dir), 256 thr.
// Sync domains: (dir, m0-half) -> 4 independent groups of 32 WGs.
// ---------------------------------------------------------------------------
#define HN_OFF ((size_t)16777216)
#define CN_OFF ((size_t)16908288)

__global__ __launch_bounds__(256, 1) void scan_kernel(
    const ushort_t* __restrict__ gx, const void* __restrict__ mask,
    const ushort_t* __restrict__ WhhT, const void* __restrict__ noiseh,
    ushort_t* __restrict__ hm, void* __restrict__ dout,
    uint32_t* __restrict__ bar, int layer, int out_use_flag,
    const uint32_t* __restrict__ flag)
{
    const uint32_t f32    = *flag;
    const uint32_t outf32 = out_use_flag ? f32 : 0u;
    const int d  = blockIdx.x >> 6;
    const int wg = blockIdx.x & 63;
    const int m0 = (wg >> 5) * 32;
    const int j0 = (wg & 31) * 16;
    const int tid = threadIdx.x;
    const int lane = tid & 63;
    const int w = tid >> 6;
    const int dom  = d * 2 + (wg >> 5);
    const int wgin = wg & 31;
    uint32_t* flags = bar + (size_t)(layer * 4 + dom) * 512;   // 2 KB per domain

    __shared__ ushort_t Wl[4 * 16 * 520];       // 66.56 KB
    __shared__ float gatesL[4][32][16];         // 8 KB

    // Load W_hh^T slice: 4 gates x 16 cols x 512 k
#pragma unroll
    for (int c = 0; c < 16; ++c) {
        int id = c * 256 + tid;
        int row = id >> 6;            // 0..63 = g*16+nn
        int kc  = (id & 63) * 8;
        int g = row >> 4, nn = row & 15;
        *(shortx8*)&Wl[(g * 16 + nn) * 520 + kc] =
            *(const shortx8*)&WhhT[(((size_t)d * 4 + g) * 512 + (j0 + nn)) * 512 + kc];
    }

    // Per-thread cells (2 each), persistent noise + state in registers
    int cb[2], cj[2];
    float nz[2][4];
    float hprev[2] = {0.f, 0.f}, cprev[2] = {0.f, 0.f};
#pragma unroll
    for (int cc = 0; cc < 2; ++cc) {
        int cell = tid + cc * 256;
        cb[cc] = m0 + (cell >> 4);
        cj[cc] = j0 + (cell & 15);
#pragma unroll
        for (int g = 0; g < 4; ++g)
            nz[cc][g] = loadf(noiseh, (((size_t)d * 4 + g) * 64 + cb[cc]) * 512 + cj[cc], f32);
        // zero BOTH ping-pong hm slots (sc1 write-through, paired u32)
        if ((tid & 1) == 0) {
            for (int p2 = 0; p2 < 2; ++p2)
#pragma unroll
                for (int g = 0; g < 4; ++g)
                    __hip_atomic_store(
                        (uint32_t*)(hm + (size_t)((p2 * 2 + d) * 4 + g) * 32768
                                       + (size_t)cb[cc] * 512 + cj[cc]),
                        0u, __ATOMIC_RELAXED, __HIP_MEMORY_SCOPE_AGENT);
        }
    }

    // gx/mask prefetch registers
    ushort_t gpre[2][4];
    float    mpre[2];
    auto ldpre = [&](int tt) {
#pragma unroll
        for (int cc = 0; cc < 2; ++cc) {
            const ushort_t* gxp = gx + ((size_t)d * 16384 + (size_t)tt * 64 + cb[cc]) * 2048 + cj[cc];
            gpre[cc][0] = gxp[0];
            gpre[cc][1] = gxp[512];
            gpre[cc][2] = gxp[1024];
            gpre[cc][3] = gxp[1536];
            mpre[cc] = loadf(mask, (size_t)tt * 64 + cb[cc], f32);
        }
    };
    ldpre(d == 0 ? 0 : 255);

    domain_barrier(flags, wgin, 1u);

    int pp = 0;
    const int mt_off = (w & 1) * 16;
    const int g0 = (w >> 1) * 2;
    const int arow = m0 + mt_off + (lane & 15);
    const int kb = (lane >> 4) * 8;

    for (int step = 0; step < 256; ++step) {
        const int t = (d == 0) ? step : (255 - step);

        // ---- MFMA: gates_partial = hm_g @ Whh_g  (this WG's rows/cols) ----
        // Register-prefetch ALL 32 A-fragments first: forces the compiler to
        // put every post-fence MALL-latency load in flight at once (one
        // latency exposure) instead of interleaving with MFMAs under a tight
        // VGPR budget (r4: VGPR=88 -> ~4-5 serialized load batches).
        floatx4 acc0 = (floatx4){0.f,0.f,0.f,0.f};
        floatx4 acc1 = (floatx4){0.f,0.f,0.f,0.f};
        const ushort_t* hmR = hm + (size_t)(pp * 2 + d) * 4 * 32768;
        const ushort_t* a0p = hmR + (size_t)(g0    ) * 32768 + (size_t)arow * 512 + kb;
        const ushort_t* a1p = hmR + (size_t)(g0 + 1) * 32768 + (size_t)arow * 512 + kb;
        const ushort_t* b0p = &Wl[((g0    ) * 16 + (lane & 15)) * 520 + kb];
        const ushort_t* b1p = &Wl[((g0 + 1) * 16 + (lane & 15)) * 520 + kb];
        shortx8 areg0[16], areg1[16];
#pragma unroll
        for (int kt = 0; kt < 16; ++kt) areg0[kt] = *(const shortx8*)(a0p + kt * 32);
#pragma unroll
        for (int kt = 0; kt < 16; ++kt) areg1[kt] = *(const shortx8*)(a1p + kt * 32);
#pragma unroll
        for (int kt = 0; kt < 16; ++kt) {
            shortx8 b0 = *(const shortx8*)(b0p + kt * 32);
            acc0 = __builtin_amdgcn_mfma_f32_16x16x32_bf16(areg0[kt], b0, acc0, 0, 0, 0);
            shortx8 b1 = *(const shortx8*)(b1p + kt * 32);
            acc1 = __builtin_amdgcn_mfma_f32_16x16x32_bf16(areg1[kt], b1, acc1, 0, 0, 0);
        }
#pragma unroll
        for (int r = 0; r < 4; ++r) {
            gatesL[g0    ][mt_off + (lane >> 4) * 4 + r][lane & 15] = acc0[r];
            gatesL[g0 + 1][mt_off + (lane >> 4) * 4 + r][lane & 15] = acc1[r];
        }
        __syncthreads();

        // ---- cell update ----
        ushort_t* hmW = hm + (size_t)((pp ^ 1) * 2 + d) * 4 * 32768;
#pragma unroll
        for (int cc = 0; cc < 2; ++cc) {
            int b = cb[cc], j = cj[cc];
            int bl = b - m0, jl = j - j0;
            float p0 = gatesL[0][bl][jl] + bf2f(gpre[cc][0]);
            float p1 = gatesL[1][bl][jl] + bf2f(gpre[cc][1]);
            float p2 = gatesL[2][bl][jl] + bf2f(gpre[cc][2]);
            float p3 = gatesL[3][bl][jl] + bf2f(gpre[cc][3]);
            float ig = 1.f / (1.f + __expf(-p0));
            float fg = 1.f / (1.f + __expf(-p1));
            float gg = tanhf(p2);
            float og = 1.f / (1.f + __expf(-p3));
            float cnew = fg * cprev[cc] + ig * gg;
            float hnew = og * tanhf(cnew);
            float mt = mpre[cc];
            float hv = hnew * mt + hprev[cc] * (1.f - mt);
            float cv = cnew * mt + cprev[cc] * (1.f - mt);
            hprev[cc] = hv; cprev[cc] = cv;
            size_t oo = ((size_t)t * 64 + b) * 1024 + (size_t)d * 512 + j;
            if (outf32) ((float*)dout)[oo] = hv;
            else        ((ushort_t*)dout)[oo] = f2bf(hv);
            // hm: paired u32 sc1 write-through stores (adjacent j in one word)
#pragma unroll
            for (int g = 0; g < 4; ++g) {
                uint32_t own = (uint32_t)f2bf(hv * nz[cc][g]);
                uint32_t oth = (uint32_t)__shfl_xor((int)own, 1, 64);
                if ((tid & 1) == 0) {
                    uint32_t word = (own & 0xffffu) | (oth << 16);
                    __hip_atomic_store(
                        (uint32_t*)(hmW + (size_t)g * 32768 + (size_t)b * 512 + j),
                        word, __ATOMIC_RELAXED, __HIP_MEMORY_SCOPE_AGENT);
                }
            }
        }
        // prefetch next step's gx+mask; latency hides under the barrier
        if (step < 255) ldpre(d == 0 ? step + 1 : 254 - step);

        domain_barrier(flags, wgin, (uint32_t)(step + 2));
        pp ^= 1;
    }

    const int slot = layer * 2 + d;
#pragma unroll
    for (int cc = 0; cc < 2; ++cc) {
        size_t ho = HN_OFF + ((size_t)slot * 64 + cb[cc]) * 512 + cj[cc];
        size_t co = CN_OFF + ((size_t)slot * 64 + cb[cc]) * 512 + cj[cc];
        if (f32) { ((float*)dout)[ho] = hprev[cc]; ((float*)dout)[co] = cprev[cc]; }
        else     { ((ushort_t*)dout)[ho] = f2bf(hprev[cc]); ((ushort_t*)dout)[co] = f2bf(cprev[cc]); }
    }
}

// ---------------------------------------------------------------------------
// Workspace layout (bytes) — total ~142 MB
// ---------------------------------------------------------------------------
#define OFF_WIH   ((size_t)0)           // W_ih^T bf16: 8,388,608 (max of layers)
#define OFF_WHH   ((size_t)8388608)     // W_hh^T bf16: 4,194,304
#define OFF_BS    ((size_t)12582912)    // bias f32:    16,384
#define OFF_BAR   ((size_t)12599296)    // barrier flags: 16,384 (8 domains x 2 KB)
#define OFF_FLAG  ((size_t)12615680)    // dtype flag:     256
#define OFF_HM    ((size_t)12615936)    // h*noise ping-pong: 2,097,152
#define OFF_GX    ((size_t)14713088)    // gx bf16: 134,217,728

extern "C" void kernel_launch(void* const* d_in, const int* in_sizes, int n_in,
                              void* d_out, int out_size, void* d_ws, size_t ws_size,
                              hipStream_t stream) {
    const void* x        = d_in[0];
    const void* mask     = d_in[1];
    const void* w_ih_l0  = d_in[2];
    const void* w_hh_l0  = d_in[3];
    const void* b_ih_l0  = d_in[4];
    const void* b_hh_l0  = d_in[5];
    const void* n_in_l0  = d_in[6];
    const void* n_hid_l0 = d_in[7];
    const void* w_ih_l1  = d_in[8];
    const void* w_hh_l1  = d_in[9];
    const void* b_ih_l1  = d_in[10];
    const void* b_hh_l1  = d_in[11];
    const void* n_in_l1  = d_in[12];
    const void* n_hid_l1 = d_in[13];

    char* ws = (char*)d_ws;
    ushort_t* WIH  = (ushort_t*)(ws + OFF_WIH);
    ushort_t* WHH  = (ushort_t*)(ws + OFF_WHH);
    float*    BS   = (float*)(ws + OFF_BS);
    uint32_t* BAR  = (uint32_t*)(ws + OFF_BAR);
    uint32_t* FLAG = (uint32_t*)(ws + OFF_FLAG);
    ushort_t* HM   = (ushort_t*)(ws + OFF_HM);
    ushort_t* GX   = (ushort_t*)(ws + OFF_GX);

    hipMemsetAsync(BAR, 0, 16384 + 256, stream);   // barrier flags + dtype flag
    detect_dtype<<<1, 256, 0, stream>>>((const ushort_t*)x, FLAG);

    // ---- layer 0 (layer-0 output staged bf16 at d_out base) ----------------
    transpose_k<<<dim3(8, 8, 8),  256, 0, stream>>>(w_ih_l0, WIH, 512, 512, FLAG);
    transpose_k<<<dim3(8, 8, 8),  256, 0, stream>>>(w_hh_l0, WHH, 512, 512, FLAG);
    bias_kernel<<<16, 256, 0, stream>>>(b_ih_l0, b_hh_l0, BS, FLAG);
    gx_gemm<<<dim3(4, 128, 8), 256, 0, stream>>>(x, n_in_l0, WIH, BS, GX, 512, FLAG, 1);
    scan_kernel<<<dim3(128), 256, 0, stream>>>(GX, mask, WHH, n_hid_l0, HM, d_out, BAR, 0, 0, FLAG);

    // ---- layer 1 (gemm consumes bf16 staging, then scan writes final) ------
    transpose_k<<<dim3(8, 16, 8), 256, 0, stream>>>(w_ih_l1, WIH, 1024, 512, FLAG);
    transpose_k<<<dim3(8, 8, 8),  256, 0, stream>>>(w_hh_l1, WHH, 512, 512, FLAG);
    bias_kernel<<<16, 256, 0, stream>>>(b_ih_l1, b_hh_l1, BS, FLAG);
    gx_gemm<<<dim3(4, 128, 8), 256, 0, stream>>>(d_out, n_in_l1, WIH, BS, GX, 1024, FLAG, 0);
    scan_kernel<<<dim3(128), 256, 0, stream>>>(GX, mask, WHH, n_hid_l1, HM, d_out, BAR, 1, 1, FLAG);
}